// Round 19
// baseline (97.800 us; speedup 1.0000x reference)
//
#include <hip/hip_runtime.h>

#define N_NODES 100000
#define N_EDGES 1600000
#define NFEAT 64
#define NCLASS 64
#define NGROUPS (N_NODES / 16)   // 6250 16-node MFMA groups, exact

// fine parts: 511 parts x 196 nodes (round-13 champion geometry)
#define PARTS 511
#define NPP 196
// bin: 256 blocks, each owns 6250 edges + private BLOCK-MAJOR staging
#define BINB 256
#define EPB (N_EDGES / BINB)     // 6250, exact
#define BCAP 48                  // per (block,part): mean 12.2, +10 sigma
#define TCAP 3712                // per part total: mean 3136, +10 sigma

typedef __attribute__((ext_vector_type(8))) short bf16x8;   // 8 bf16 = 4 VGPRs
typedef __attribute__((ext_vector_type(4))) float f32x4;

__device__ inline unsigned short f2bf(float f) {   // round-to-nearest-even
    union { float f; unsigned u; } v; v.f = f;
    unsigned u = v.u + 0x7fffu + ((v.u >> 16) & 1u);
    return (unsigned short)(u >> 16);
}
__device__ inline float bf2f(unsigned short s) {
    union { unsigned u; float f; } v; v.u = ((unsigned)s) << 16;
    return v.f;
}

// ---------------------------------------------------------------------------
// prepbin: blocks [0,BINB) bin edges (BLOCK-MAJOR private staging, LDS
// cursors only, zero global atomics); blocks [BINB,..) x->bf16 + Wcat.
// adj reads are stream-once -> nontemporal (no L2 allocate).
// ---------------------------------------------------------------------------
#define X_ITEMS (N_NODES * NFEAT / 4)          // 1,600,000 float4->ushort4
#define W_ITEMS (NCLASS * 128)                 // 8,192 scalar
__global__ __launch_bounds__(256) void prepbin_kernel(
    const float4* __restrict__ x4, ushort4* __restrict__ xb4,
    const float* __restrict__ W_rel, const float* __restrict__ W_root,
    unsigned short* __restrict__ Wcat,
    const int* __restrict__ src, const int* __restrict__ dst,
    int* __restrict__ counts,
    unsigned* __restrict__ staging) {          // = (unsigned*)d_out, blk-major
    __shared__ int cur[PARTS];
    const int tid = threadIdx.x;
    if (blockIdx.x < BINB) {
        const int blk = blockIdx.x;
        for (int i = tid; i < PARTS; i += 256) cur[i] = 0;
        __syncthreads();
        const int e0 = blk * EPB;
        for (int r = tid; r < EPB; r += 256) {
            int e = e0 + r;
            unsigned d = (unsigned)__builtin_nontemporal_load(&dst[e]);
            unsigned s = (unsigned)__builtin_nontemporal_load(&src[e]);
            unsigned p = d / (unsigned)NPP;          // magic-mul
            unsigned dl = d - p * (unsigned)NPP;
            int pos = atomicAdd(&cur[p], 1);         // LDS only
            if (pos < BCAP)                           // block-major: contiguous
                staging[((size_t)blk * PARTS + p) * BCAP + pos] = (dl << 17) | s;
        }
        __syncthreads();
        for (int i = tid; i < PARTS; i += 256)
            counts[blk * PARTS + i] = min(cur[i], BCAP);
    } else {
        int i = (blockIdx.x - BINB) * 256 + tid;
        int stride = (gridDim.x - BINB) * 256;
        for (; i < X_ITEMS + W_ITEMS; i += stride) {
            if (i < X_ITEMS) {
                float4 v = x4[i];
                ushort4 o;
                o.x = f2bf(v.x); o.y = f2bf(v.y); o.z = f2bf(v.z); o.w = f2bf(v.w);
                xb4[i] = o;
            } else {
                int j = i - X_ITEMS;
                int c = j >> 7, k = j & 127;
                float v = (k < 64) ? W_rel[c * 64 + k] : W_root[c * 64 + (k - 64)];
                Wcat[j] = f2bf(v);
            }
        }
    }
}

// ---------------------------------------------------------------------------
// aggsort (round-17 champion): LDS list -> counting sort -> per-node wave
// gather with 8 rows in flight (r18: unroll-16 was null -> queue-saturated).
// Staging reads are stream-once -> nontemporal, preserving x_bf L2 residency
// for the latency-bound gather.
// ---------------------------------------------------------------------------
__global__ __launch_bounds__(1024) void aggsort_kernel(
    const unsigned short* __restrict__ x_bf,
    const int* __restrict__ counts,
    const unsigned* __restrict__ staging,
    unsigned short* __restrict__ agg_bf) {
    __shared__ unsigned list[TCAP];
    __shared__ unsigned slot[TCAP];
    __shared__ int segorig[BINB], segscan[BINB], segoff[BINB];
    __shared__ int cnt[NPP], nodeoff[NPP], curn[NPP];
    __shared__ int scan256[256];

    const int p = blockIdx.x;
    const int tid = threadIdx.x;

    // 1. per-segment counts + inclusive scan over 256
    if (tid < BINB) {
        int c = counts[tid * PARTS + p];
        segorig[tid] = c;
        segscan[tid] = c;
    }
    __syncthreads();
    for (int off = 1; off < BINB; off <<= 1) {
        int v = 0;
        if (tid < BINB && tid >= off) v = segscan[tid - off];
        __syncthreads();
        if (tid < BINB && tid >= off) segscan[tid] += v;
        __syncthreads();
    }
    if (tid < BINB) segoff[tid] = segscan[tid] - segorig[tid];  // exclusive
    __syncthreads();
    const int total = min(segscan[BINB - 1], TCAP);

    // copy segments into dense LDS list (nontemporal stream-once read)
    for (int k = tid; k < BINB * BCAP; k += 1024) {
        int seg = k / BCAP;
        int idx = k - seg * BCAP;
        if (idx < segorig[seg]) {
            int dp = segoff[seg] + idx;
            if (dp < TCAP)
                list[dp] = __builtin_nontemporal_load(
                    &staging[((size_t)seg * PARTS + p) * BCAP + idx]);
        }
    }
    // 2a. node histogram
    for (int i = tid; i < NPP; i += 1024) cnt[i] = 0;
    __syncthreads();
    for (int i = tid; i < total; i += 1024)
        atomicAdd(&cnt[list[i] >> 17], 1);
    __syncthreads();
    // 2b. inclusive scan over 196 (padded to 256)
    if (tid < 256) scan256[tid] = (tid < NPP) ? cnt[tid] : 0;
    __syncthreads();
    for (int off = 1; off < 256; off <<= 1) {
        int v = 0;
        if (tid < 256 && tid >= off) v = scan256[tid - off];
        __syncthreads();
        if (tid < 256 && tid >= off) scan256[tid] += v;
        __syncthreads();
    }
    if (tid < NPP) {
        int st = scan256[tid] - cnt[tid];   // exclusive
        nodeoff[tid] = st;
        curn[tid] = st;
    }
    __syncthreads();
    // 2c. scatter into sorted order (keep only src, 17 bits)
    for (int i = tid; i < total; i += 1024) {
        unsigned v = list[i];
        int r = (int)(v >> 17);
        int pos = atomicAdd(&curn[r], 1);
        slot[pos] = v & 0x1FFFFu;
    }
    __syncthreads();

    // 3. per-node wave gather, 8 rows in flight (r17-proven sweet spot)
    const int lane = tid & 63;
    const int w = tid >> 6;            // 0..15
    for (int r = w; r < NPP; r += 16) {
        int node = p * NPP + r;
        if (node >= N_NODES) break;    // wave-uniform
        int beg = nodeoff[r];
        int end = beg + cnt[r];
        float acc0 = 0.f, acc1 = 0.f;
        int j = beg;
        for (; j + 8 <= end; j += 8) {
            int s0 = (int)slot[j + 0];
            int s1 = (int)slot[j + 1];
            int s2 = (int)slot[j + 2];
            int s3 = (int)slot[j + 3];
            int s4 = (int)slot[j + 4];
            int s5 = (int)slot[j + 5];
            int s6 = (int)slot[j + 6];
            int s7 = (int)slot[j + 7];
            float v0 = bf2f(x_bf[(size_t)s0 * 64 + lane]);
            float v1 = bf2f(x_bf[(size_t)s1 * 64 + lane]);
            float v2 = bf2f(x_bf[(size_t)s2 * 64 + lane]);
            float v3 = bf2f(x_bf[(size_t)s3 * 64 + lane]);
            float v4 = bf2f(x_bf[(size_t)s4 * 64 + lane]);
            float v5 = bf2f(x_bf[(size_t)s5 * 64 + lane]);
            float v6 = bf2f(x_bf[(size_t)s6 * 64 + lane]);
            float v7 = bf2f(x_bf[(size_t)s7 * 64 + lane]);
            acc0 += v0; acc1 += v1; acc0 += v2; acc1 += v3;
            acc0 += v4; acc1 += v5; acc0 += v6; acc1 += v7;
        }
        for (; j + 4 <= end; j += 4) {
            int s0 = (int)slot[j + 0];
            int s1 = (int)slot[j + 1];
            int s2 = (int)slot[j + 2];
            int s3 = (int)slot[j + 3];
            float v0 = bf2f(x_bf[(size_t)s0 * 64 + lane]);
            float v1 = bf2f(x_bf[(size_t)s1 * 64 + lane]);
            float v2 = bf2f(x_bf[(size_t)s2 * 64 + lane]);
            float v3 = bf2f(x_bf[(size_t)s3 * 64 + lane]);
            acc0 += v0; acc1 += v1; acc0 += v2; acc1 += v3;
        }
        for (; j < end; ++j) acc0 += bf2f(x_bf[(size_t)slot[j] * 64 + lane]);
        agg_bf[(size_t)node * 64 + lane] = f2bf(acc0 + acc1);
    }
}

// ---------------------------------------------------------------------------
// MFMA transform (round-8 proven): out[n][c] = relu(agg.Wrel + x.Wroot + b)
// ---------------------------------------------------------------------------
__global__ __launch_bounds__(256, 2) void transform_mfma_kernel(
    const unsigned short* __restrict__ agg_bf,  // [N][64] bf16
    const unsigned short* __restrict__ x_bf,    // [N][64] bf16
    const unsigned short* __restrict__ Wcat,    // [64][128] bf16
    const float* __restrict__ b_rel,
    float* __restrict__ out) {
    const int lane = threadIdx.x & 63;
    const int lr = lane & 15;
    const int lh = lane >> 4;

    bf16x8 bfr[4][4];
    #pragma unroll
    for (int cg = 0; cg < 4; ++cg)
        #pragma unroll
        for (int kk = 0; kk < 4; ++kk)
            bfr[cg][kk] = *(const bf16x8*)(Wcat + (cg * 16 + lr) * 128 + kk * 32 + lh * 8);

    float bias[4];
    #pragma unroll
    for (int cg = 0; cg < 4; ++cg) bias[cg] = b_rel[cg * 16 + lr];

    int wid = (blockIdx.x * blockDim.x + threadIdx.x) >> 6;
    int nw  = (gridDim.x * blockDim.x) >> 6;

    for (int g = wid; g < NGROUPS; g += nw) {
        const unsigned short* Aa = agg_bf + (size_t)(g * 16 + lr) * 64;
        const unsigned short* Ax = x_bf   + (size_t)(g * 16 + lr) * 64;
        bf16x8 afr[4];
        #pragma unroll
        for (int kk = 0; kk < 2; ++kk) {
            afr[kk]     = *(const bf16x8*)(Aa + kk * 32 + lh * 8);
            afr[kk + 2] = *(const bf16x8*)(Ax + kk * 32 + lh * 8);
        }
        #pragma unroll
        for (int cg = 0; cg < 4; ++cg) {
            f32x4 acc = {0.f, 0.f, 0.f, 0.f};
            #pragma unroll
            for (int kk = 0; kk < 4; ++kk)
                acc = __builtin_amdgcn_mfma_f32_16x16x32_bf16(afr[kk], bfr[cg][kk], acc, 0, 0, 0);
            #pragma unroll
            for (int r = 0; r < 4; ++r)
                out[(size_t)(g * 16 + lh * 4 + r) * 64 + cg * 16 + lr] =
                    fmaxf(acc[r] + bias[cg], 0.f);
        }
    }
}

// ---------------------------------------------------------------------------
// Fallback path (needs no workspace): atomic scatter + fp32 transform
// ---------------------------------------------------------------------------
__global__ void zero_kernel(float4* __restrict__ p, int n4) {
    int i = blockIdx.x * blockDim.x + threadIdx.x;
    int stride = gridDim.x * blockDim.x;
    for (; i < n4; i += stride) p[i] = make_float4(0.f, 0.f, 0.f, 0.f);
}

__global__ void scatter_kernel(const float4* __restrict__ x4,
                               const int* __restrict__ src,
                               const int* __restrict__ dst,
                               float* __restrict__ agg) {
    int idx = blockIdx.x * blockDim.x + threadIdx.x;
    const int total = N_EDGES * 16;
    int stride = gridDim.x * blockDim.x;
    for (; idx < total; idx += stride) {
        int e = idx >> 4;
        int q = idx & 15;
        int s = src[e];
        int d = dst[e];
        float4 v = x4[s * 16 + q];
        float* base = agg + d * 64 + q * 4;
        unsafeAtomicAdd(base + 0, v.x);
        unsafeAtomicAdd(base + 1, v.y);
        unsafeAtomicAdd(base + 2, v.z);
        unsafeAtomicAdd(base + 3, v.w);
    }
}

__global__ __launch_bounds__(256, 1) void transform3_kernel(
    const float* __restrict__ x,
    const float* __restrict__ W_rel,
    const float* __restrict__ b_rel,
    const float* __restrict__ W_root,
    float* __restrict__ agg_out) {
    const int lane = threadIdx.x & 63;
    float4 wr[16], wo[16];
    const float4* Wr4 = (const float4*)W_rel;
    const float4* Wo4 = (const float4*)W_root;
    #pragma unroll
    for (int i = 0; i < 16; ++i) {
        float4 a = Wr4[lane * 16 + i];
        float4 b = Wo4[lane * 16 + i];
        asm volatile("" : "+v"(a.x), "+v"(a.y), "+v"(a.z), "+v"(a.w));
        asm volatile("" : "+v"(b.x), "+v"(b.y), "+v"(b.z), "+v"(b.w));
        wr[i] = a;
        wo[i] = b;
    }
    const float bias = b_rel[lane];
    int gwave = (blockIdx.x * blockDim.x + threadIdx.x) >> 6;
    int nwaves = (gridDim.x * blockDim.x) >> 6;
    for (int node = gwave; node < N_NODES; node += nwaves) {
        const float4* ar4 = (const float4*)(agg_out + (size_t)node * 64);
        const float4* xr4 = (const float4*)(x + (size_t)node * 64);
        float acc = bias;
        #pragma unroll
        for (int i = 0; i < 16; ++i) {
            float4 a = ar4[i];
            float4 v = xr4[i];
            acc += a.x * wr[i].x + a.y * wr[i].y + a.z * wr[i].z + a.w * wr[i].w;
            acc += v.x * wo[i].x + v.y * wo[i].y + v.z * wo[i].z + v.w * wo[i].w;
        }
        agg_out[(size_t)node * 64 + lane] = fmaxf(acc, 0.f);
    }
}

extern "C" void kernel_launch(void* const* d_in, const int* in_sizes, int n_in,
                              void* d_out, int out_size, void* d_ws, size_t ws_size,
                              hipStream_t stream) {
    const float* x      = (const float*)d_in[0];
    const int*   adj    = (const int*)d_in[1];   // delivered as int32 [2][N_EDGES]
    const float* W_rel  = (const float*)d_in[2];
    const float* b_rel  = (const float*)d_in[3];
    const float* W_root = (const float*)d_in[4];
    float*       out    = (float*)d_out;

    const int* src = adj;
    const int* dst = adj + N_EDGES;

    // ws: counts[BINB*PARTS] ints | x_bf | agg_bf | Wcat (bf16)
    // staging (256 blk x 511 parts x 48 x 4B = 25.1MB, BLOCK-major) lives in
    // d_out (25.6MB), fully consumed by aggsort BEFORE transform writes d_out.
    const size_t CNT_INTS = (size_t)BINB * PARTS;          // 130,816
    const size_t row_elems = (size_t)N_NODES * 64;
    const size_t bf_base = ((CNT_INTS * sizeof(int)) + 127) & ~(size_t)127;
    const size_t ws_needed = bf_base +
        (2 * row_elems + (size_t)NCLASS * 128) * sizeof(unsigned short);

    if (ws_size >= ws_needed) {
        int* counts = (int*)d_ws;
        unsigned short* x_bf   = (unsigned short*)((char*)d_ws + bf_base);
        unsigned short* agg_bf = x_bf + row_elems;
        unsigned short* Wcat   = agg_bf + row_elems;
        unsigned* staging = (unsigned*)d_out;

        prepbin_kernel<<<BINB + 2048, 256, 0, stream>>>(
            (const float4*)x, (ushort4*)x_bf, W_rel, W_root, Wcat,
            src, dst, counts, staging);
        aggsort_kernel<<<PARTS, 1024, 0, stream>>>(x_bf, counts, staging, agg_bf);
        transform_mfma_kernel<<<1024, 256, 0, stream>>>(agg_bf, x_bf, Wcat, b_rel, out);
    } else {
        zero_kernel<<<2048, 256, 0, stream>>>((float4*)out, (N_NODES * NFEAT) / 4);
        scatter_kernel<<<4096, 256, 0, stream>>>((const float4*)x, src, dst, out);
        transform3_kernel<<<1024, 256, 0, stream>>>(x, W_rel, b_rel, W_root, out);
    }
}

// Round 20
// 84.524 us; speedup vs baseline: 1.1571x; 1.1571x over previous
//
#include <hip/hip_runtime.h>

#define N_NODES 100000
#define N_EDGES 1600000
#define NFEAT 64
#define NCLASS 64
#define NGROUPS (N_NODES / 16)   // 6250 16-node MFMA groups, exact

// fine parts: 511 parts x 196 nodes (round-13 champion geometry)
#define PARTS 511
#define NPP 196
// bin: 256 blocks, each owns 6250 edges + private BLOCK-MAJOR staging
#define BINB 256
#define EPB (N_EDGES / BINB)     // 6250, exact
#define BCAP 48                  // per (block,part): mean 12.2, +10 sigma
#define TCAP 3712                // per part total: mean 3136, +10 sigma

typedef __attribute__((ext_vector_type(8))) short bf16x8;   // 8 bf16 = 4 VGPRs
typedef __attribute__((ext_vector_type(4))) float f32x4;

__device__ inline unsigned short f2bf(float f) {   // round-to-nearest-even
    union { float f; unsigned u; } v; v.f = f;
    unsigned u = v.u + 0x7fffu + ((v.u >> 16) & 1u);
    return (unsigned short)(u >> 16);
}
__device__ inline float bf2f(unsigned short s) {
    union { unsigned u; float f; } v; v.u = ((unsigned)s) << 16;
    return v.f;
}

// ---------------------------------------------------------------------------
// prepbin: blocks [0,BINB) bin edges (BLOCK-MAJOR private staging, LDS
// cursors only, zero global atomics); blocks [BINB,..) x->bf16 + Wcat.
// NOTE r19: nontemporal loads on adj REGRESSED ~13us -- plain loads here.
// ---------------------------------------------------------------------------
#define X_ITEMS (N_NODES * NFEAT / 4)          // 1,600,000 float4->ushort4
#define W_ITEMS (NCLASS * 128)                 // 8,192 scalar
__global__ __launch_bounds__(256) void prepbin_kernel(
    const float4* __restrict__ x4, ushort4* __restrict__ xb4,
    const float* __restrict__ W_rel, const float* __restrict__ W_root,
    unsigned short* __restrict__ Wcat,
    const int* __restrict__ src, const int* __restrict__ dst,
    int* __restrict__ counts,
    unsigned* __restrict__ staging) {          // = (unsigned*)d_out, blk-major
    __shared__ int cur[PARTS];
    const int tid = threadIdx.x;
    if (blockIdx.x < BINB) {
        const int blk = blockIdx.x;
        for (int i = tid; i < PARTS; i += 256) cur[i] = 0;
        __syncthreads();
        const int e0 = blk * EPB;
        for (int r = tid; r < EPB; r += 256) {
            int e = e0 + r;
            unsigned d = (unsigned)dst[e];           // coalesced
            unsigned s = (unsigned)src[e];           // coalesced
            unsigned p = d / (unsigned)NPP;          // magic-mul
            unsigned dl = d - p * (unsigned)NPP;
            int pos = atomicAdd(&cur[p], 1);         // LDS only
            if (pos < BCAP)                           // block-major: contiguous
                staging[((size_t)blk * PARTS + p) * BCAP + pos] = (dl << 17) | s;
        }
        __syncthreads();
        for (int i = tid; i < PARTS; i += 256)
            counts[blk * PARTS + i] = min(cur[i], BCAP);
    } else {
        int i = (blockIdx.x - BINB) * 256 + tid;
        int stride = (gridDim.x - BINB) * 256;
        for (; i < X_ITEMS + W_ITEMS; i += stride) {
            if (i < X_ITEMS) {
                float4 v = x4[i];
                ushort4 o;
                o.x = f2bf(v.x); o.y = f2bf(v.y); o.z = f2bf(v.z); o.w = f2bf(v.w);
                xb4[i] = o;
            } else {
                int j = i - X_ITEMS;
                int c = j >> 7, k = j & 127;
                float v = (k < 64) ? W_rel[c * 64 + k] : W_root[c * 64 + (k - 64)];
                Wcat[j] = f2bf(v);
            }
        }
    }
}

// ---------------------------------------------------------------------------
// aggsort (round-17 champion): LDS list -> counting sort -> per-node wave
// gather with 8 rows in flight. r18: unroll-16 null (queue-saturated);
// r19: nontemporal staging reads null (FETCH unchanged). This phase is at
// the scattered-row service floor: 205MB logical random 128B rows ~5.9TB/s
// through L2/L3 at 63% occupancy.
// ---------------------------------------------------------------------------
__global__ __launch_bounds__(1024) void aggsort_kernel(
    const unsigned short* __restrict__ x_bf,
    const int* __restrict__ counts,
    const unsigned* __restrict__ staging,
    unsigned short* __restrict__ agg_bf) {
    __shared__ unsigned list[TCAP];
    __shared__ unsigned slot[TCAP];
    __shared__ int segorig[BINB], segscan[BINB], segoff[BINB];
    __shared__ int cnt[NPP], nodeoff[NPP], curn[NPP];
    __shared__ int scan256[256];

    const int p = blockIdx.x;
    const int tid = threadIdx.x;

    // 1. per-segment counts + inclusive scan over 256
    if (tid < BINB) {
        int c = counts[tid * PARTS + p];
        segorig[tid] = c;
        segscan[tid] = c;
    }
    __syncthreads();
    for (int off = 1; off < BINB; off <<= 1) {
        int v = 0;
        if (tid < BINB && tid >= off) v = segscan[tid - off];
        __syncthreads();
        if (tid < BINB && tid >= off) segscan[tid] += v;
        __syncthreads();
    }
    if (tid < BINB) segoff[tid] = segscan[tid] - segorig[tid];  // exclusive
    __syncthreads();
    const int total = min(segscan[BINB - 1], TCAP);

    // copy segments into dense LDS list
    for (int k = tid; k < BINB * BCAP; k += 1024) {
        int seg = k / BCAP;
        int idx = k - seg * BCAP;
        if (idx < segorig[seg]) {
            int dp = segoff[seg] + idx;
            if (dp < TCAP)
                list[dp] = staging[((size_t)seg * PARTS + p) * BCAP + idx];
        }
    }
    // 2a. node histogram
    for (int i = tid; i < NPP; i += 1024) cnt[i] = 0;
    __syncthreads();
    for (int i = tid; i < total; i += 1024)
        atomicAdd(&cnt[list[i] >> 17], 1);
    __syncthreads();
    // 2b. inclusive scan over 196 (padded to 256)
    if (tid < 256) scan256[tid] = (tid < NPP) ? cnt[tid] : 0;
    __syncthreads();
    for (int off = 1; off < 256; off <<= 1) {
        int v = 0;
        if (tid < 256 && tid >= off) v = scan256[tid - off];
        __syncthreads();
        if (tid < 256 && tid >= off) scan256[tid] += v;
        __syncthreads();
    }
    if (tid < NPP) {
        int st = scan256[tid] - cnt[tid];   // exclusive
        nodeoff[tid] = st;
        curn[tid] = st;
    }
    __syncthreads();
    // 2c. scatter into sorted order (keep only src, 17 bits)
    for (int i = tid; i < total; i += 1024) {
        unsigned v = list[i];
        int r = (int)(v >> 17);
        int pos = atomicAdd(&curn[r], 1);
        slot[pos] = v & 0x1FFFFu;
    }
    __syncthreads();

    // 3. per-node wave gather, 8 rows in flight (r17-proven sweet spot)
    const int lane = tid & 63;
    const int w = tid >> 6;            // 0..15
    for (int r = w; r < NPP; r += 16) {
        int node = p * NPP + r;
        if (node >= N_NODES) break;    // wave-uniform
        int beg = nodeoff[r];
        int end = beg + cnt[r];
        float acc0 = 0.f, acc1 = 0.f;
        int j = beg;
        for (; j + 8 <= end; j += 8) {
            int s0 = (int)slot[j + 0];
            int s1 = (int)slot[j + 1];
            int s2 = (int)slot[j + 2];
            int s3 = (int)slot[j + 3];
            int s4 = (int)slot[j + 4];
            int s5 = (int)slot[j + 5];
            int s6 = (int)slot[j + 6];
            int s7 = (int)slot[j + 7];
            float v0 = bf2f(x_bf[(size_t)s0 * 64 + lane]);
            float v1 = bf2f(x_bf[(size_t)s1 * 64 + lane]);
            float v2 = bf2f(x_bf[(size_t)s2 * 64 + lane]);
            float v3 = bf2f(x_bf[(size_t)s3 * 64 + lane]);
            float v4 = bf2f(x_bf[(size_t)s4 * 64 + lane]);
            float v5 = bf2f(x_bf[(size_t)s5 * 64 + lane]);
            float v6 = bf2f(x_bf[(size_t)s6 * 64 + lane]);
            float v7 = bf2f(x_bf[(size_t)s7 * 64 + lane]);
            acc0 += v0; acc1 += v1; acc0 += v2; acc1 += v3;
            acc0 += v4; acc1 += v5; acc0 += v6; acc1 += v7;
        }
        for (; j + 4 <= end; j += 4) {
            int s0 = (int)slot[j + 0];
            int s1 = (int)slot[j + 1];
            int s2 = (int)slot[j + 2];
            int s3 = (int)slot[j + 3];
            float v0 = bf2f(x_bf[(size_t)s0 * 64 + lane]);
            float v1 = bf2f(x_bf[(size_t)s1 * 64 + lane]);
            float v2 = bf2f(x_bf[(size_t)s2 * 64 + lane]);
            float v3 = bf2f(x_bf[(size_t)s3 * 64 + lane]);
            acc0 += v0; acc1 += v1; acc0 += v2; acc1 += v3;
        }
        for (; j < end; ++j) acc0 += bf2f(x_bf[(size_t)slot[j] * 64 + lane]);
        agg_bf[(size_t)node * 64 + lane] = f2bf(acc0 + acc1);
    }
}

// ---------------------------------------------------------------------------
// MFMA transform (round-8 proven): out[n][c] = relu(agg.Wrel + x.Wroot + b)
// ---------------------------------------------------------------------------
__global__ __launch_bounds__(256, 2) void transform_mfma_kernel(
    const unsigned short* __restrict__ agg_bf,  // [N][64] bf16
    const unsigned short* __restrict__ x_bf,    // [N][64] bf16
    const unsigned short* __restrict__ Wcat,    // [64][128] bf16
    const float* __restrict__ b_rel,
    float* __restrict__ out) {
    const int lane = threadIdx.x & 63;
    const int lr = lane & 15;
    const int lh = lane >> 4;

    bf16x8 bfr[4][4];
    #pragma unroll
    for (int cg = 0; cg < 4; ++cg)
        #pragma unroll
        for (int kk = 0; kk < 4; ++kk)
            bfr[cg][kk] = *(const bf16x8*)(Wcat + (cg * 16 + lr) * 128 + kk * 32 + lh * 8);

    float bias[4];
    #pragma unroll
    for (int cg = 0; cg < 4; ++cg) bias[cg] = b_rel[cg * 16 + lr];

    int wid = (blockIdx.x * blockDim.x + threadIdx.x) >> 6;
    int nw  = (gridDim.x * blockDim.x) >> 6;

    for (int g = wid; g < NGROUPS; g += nw) {
        const unsigned short* Aa = agg_bf + (size_t)(g * 16 + lr) * 64;
        const unsigned short* Ax = x_bf   + (size_t)(g * 16 + lr) * 64;
        bf16x8 afr[4];
        #pragma unroll
        for (int kk = 0; kk < 2; ++kk) {
            afr[kk]     = *(const bf16x8*)(Aa + kk * 32 + lh * 8);
            afr[kk + 2] = *(const bf16x8*)(Ax + kk * 32 + lh * 8);
        }
        #pragma unroll
        for (int cg = 0; cg < 4; ++cg) {
            f32x4 acc = {0.f, 0.f, 0.f, 0.f};
            #pragma unroll
            for (int kk = 0; kk < 4; ++kk)
                acc = __builtin_amdgcn_mfma_f32_16x16x32_bf16(afr[kk], bfr[cg][kk], acc, 0, 0, 0);
            #pragma unroll
            for (int r = 0; r < 4; ++r)
                out[(size_t)(g * 16 + lh * 4 + r) * 64 + cg * 16 + lr] =
                    fmaxf(acc[r] + bias[cg], 0.f);
        }
    }
}

// ---------------------------------------------------------------------------
// Fallback path (needs no workspace): atomic scatter + fp32 transform
// ---------------------------------------------------------------------------
__global__ void zero_kernel(float4* __restrict__ p, int n4) {
    int i = blockIdx.x * blockDim.x + threadIdx.x;
    int stride = gridDim.x * blockDim.x;
    for (; i < n4; i += stride) p[i] = make_float4(0.f, 0.f, 0.f, 0.f);
}

__global__ void scatter_kernel(const float4* __restrict__ x4,
                               const int* __restrict__ src,
                               const int* __restrict__ dst,
                               float* __restrict__ agg) {
    int idx = blockIdx.x * blockDim.x + threadIdx.x;
    const int total = N_EDGES * 16;
    int stride = gridDim.x * blockDim.x;
    for (; idx < total; idx += stride) {
        int e = idx >> 4;
        int q = idx & 15;
        int s = src[e];
        int d = dst[e];
        float4 v = x4[s * 16 + q];
        float* base = agg + d * 64 + q * 4;
        unsafeAtomicAdd(base + 0, v.x);
        unsafeAtomicAdd(base + 1, v.y);
        unsafeAtomicAdd(base + 2, v.z);
        unsafeAtomicAdd(base + 3, v.w);
    }
}

__global__ __launch_bounds__(256, 1) void transform3_kernel(
    const float* __restrict__ x,
    const float* __restrict__ W_rel,
    const float* __restrict__ b_rel,
    const float* __restrict__ W_root,
    float* __restrict__ agg_out) {
    const int lane = threadIdx.x & 63;
    float4 wr[16], wo[16];
    const float4* Wr4 = (const float4*)W_rel;
    const float4* Wo4 = (const float4*)W_root;
    #pragma unroll
    for (int i = 0; i < 16; ++i) {
        float4 a = Wr4[lane * 16 + i];
        float4 b = Wo4[lane * 16 + i];
        asm volatile("" : "+v"(a.x), "+v"(a.y), "+v"(a.z), "+v"(a.w));
        asm volatile("" : "+v"(b.x), "+v"(b.y), "+v"(b.z), "+v"(b.w));
        wr[i] = a;
        wo[i] = b;
    }
    const float bias = b_rel[lane];
    int gwave = (blockIdx.x * blockDim.x + threadIdx.x) >> 6;
    int nwaves = (gridDim.x * blockDim.x) >> 6;
    for (int node = gwave; node < N_NODES; node += nwaves) {
        const float4* ar4 = (const float4*)(agg_out + (size_t)node * 64);
        const float4* xr4 = (const float4*)(x + (size_t)node * 64);
        float acc = bias;
        #pragma unroll
        for (int i = 0; i < 16; ++i) {
            float4 a = ar4[i];
            float4 v = xr4[i];
            acc += a.x * wr[i].x + a.y * wr[i].y + a.z * wr[i].z + a.w * wr[i].w;
            acc += v.x * wo[i].x + v.y * wo[i].y + v.z * wo[i].z + v.w * wo[i].w;
        }
        agg_out[(size_t)node * 64 + lane] = fmaxf(acc, 0.f);
    }
}

extern "C" void kernel_launch(void* const* d_in, const int* in_sizes, int n_in,
                              void* d_out, int out_size, void* d_ws, size_t ws_size,
                              hipStream_t stream) {
    const float* x      = (const float*)d_in[0];
    const int*   adj    = (const int*)d_in[1];   // delivered as int32 [2][N_EDGES]
    const float* W_rel  = (const float*)d_in[2];
    const float* b_rel  = (const float*)d_in[3];
    const float* W_root = (const float*)d_in[4];
    float*       out    = (float*)d_out;

    const int* src = adj;
    const int* dst = adj + N_EDGES;

    // ws: counts[BINB*PARTS] ints | x_bf | agg_bf | Wcat (bf16)
    // staging (256 blk x 511 parts x 48 x 4B = 25.1MB, BLOCK-major) lives in
    // d_out (25.6MB), fully consumed by aggsort BEFORE transform writes d_out.
    const size_t CNT_INTS = (size_t)BINB * PARTS;          // 130,816
    const size_t row_elems = (size_t)N_NODES * 64;
    const size_t bf_base = ((CNT_INTS * sizeof(int)) + 127) & ~(size_t)127;
    const size_t ws_needed = bf_base +
        (2 * row_elems + (size_t)NCLASS * 128) * sizeof(unsigned short);

    if (ws_size >= ws_needed) {
        int* counts = (int*)d_ws;
        unsigned short* x_bf   = (unsigned short*)((char*)d_ws + bf_base);
        unsigned short* agg_bf = x_bf + row_elems;
        unsigned short* Wcat   = agg_bf + row_elems;
        unsigned* staging = (unsigned*)d_out;

        prepbin_kernel<<<BINB + 2048, 256, 0, stream>>>(
            (const float4*)x, (ushort4*)x_bf, W_rel, W_root, Wcat,
            src, dst, counts, staging);
        aggsort_kernel<<<PARTS, 1024, 0, stream>>>(x_bf, counts, staging, agg_bf);
        transform_mfma_kernel<<<1024, 256, 0, stream>>>(agg_bf, x_bf, Wcat, b_rel, out);
    } else {
        zero_kernel<<<2048, 256, 0, stream>>>((float4*)out, (N_NODES * NFEAT) / 4);
        scatter_kernel<<<4096, 256, 0, stream>>>((const float4*)x, src, dst, out);
        transform3_kernel<<<1024, 256, 0, stream>>>(x, W_rel, b_rel, W_root, out);
    }
}

// Round 21
// 80.796 us; speedup vs baseline: 1.2105x; 1.0461x over previous
//
#include <hip/hip_runtime.h>

#define N_NODES 100000
#define N_EDGES 1600000
#define NFEAT 64
#define NCLASS 64
#define NGROUPS (N_NODES / 16)   // 6250 16-node MFMA groups, exact

// fine parts: 511 parts x 196 nodes (round-13 champion geometry)
#define PARTS 511
#define NPP 196
// bin: 256 blocks, each owns 6250 edges + private BLOCK-MAJOR staging
#define BINB 256
#define EPB (N_EDGES / BINB)     // 6250, exact
#define BCAP 48                  // per (block,part): mean 12.2, +10 sigma
#define TCAP 3712                // per part total: mean 3136, +10 sigma

typedef __attribute__((ext_vector_type(8))) short bf16x8;   // 8 bf16 = 4 VGPRs
typedef __attribute__((ext_vector_type(4))) float f32x4;

__device__ inline unsigned short f2bf(float f) {   // round-to-nearest-even
    union { float f; unsigned u; } v; v.f = f;
    unsigned u = v.u + 0x7fffu + ((v.u >> 16) & 1u);
    return (unsigned short)(u >> 16);
}
__device__ inline float bf2f(unsigned short s) {
    union { unsigned u; float f; } v; v.u = ((unsigned)s) << 16;
    return v.f;
}

// ---------------------------------------------------------------------------
// prepbin: blocks [0,BINB) bin edges (BLOCK-MAJOR private staging, LDS
// cursors only, zero global atomics); blocks [BINB,..) x->bf16 + Wcat.
// NOTE r19: nontemporal loads on adj REGRESSED ~13us -- plain loads here.
// ---------------------------------------------------------------------------
#define X_ITEMS (N_NODES * NFEAT / 4)          // 1,600,000 float4->ushort4
#define W_ITEMS (NCLASS * 128)                 // 8,192 scalar
__global__ __launch_bounds__(256) void prepbin_kernel(
    const float4* __restrict__ x4, ushort4* __restrict__ xb4,
    const float* __restrict__ W_rel, const float* __restrict__ W_root,
    unsigned short* __restrict__ Wcat,
    const int* __restrict__ src, const int* __restrict__ dst,
    int* __restrict__ counts,
    unsigned* __restrict__ staging) {          // = (unsigned*)d_out, blk-major
    __shared__ int cur[PARTS];
    const int tid = threadIdx.x;
    if (blockIdx.x < BINB) {
        const int blk = blockIdx.x;
        for (int i = tid; i < PARTS; i += 256) cur[i] = 0;
        __syncthreads();
        const int e0 = blk * EPB;
        for (int r = tid; r < EPB; r += 256) {
            int e = e0 + r;
            unsigned d = (unsigned)dst[e];           // coalesced
            unsigned s = (unsigned)src[e];           // coalesced
            unsigned p = d / (unsigned)NPP;          // magic-mul
            unsigned dl = d - p * (unsigned)NPP;
            int pos = atomicAdd(&cur[p], 1);         // LDS only
            if (pos < BCAP)                           // block-major: contiguous
                staging[((size_t)blk * PARTS + p) * BCAP + pos] = (dl << 17) | s;
        }
        __syncthreads();
        for (int i = tid; i < PARTS; i += 256)
            counts[blk * PARTS + i] = min(cur[i], BCAP);
    } else {
        int i = (blockIdx.x - BINB) * 256 + tid;
        int stride = (gridDim.x - BINB) * 256;
        for (; i < X_ITEMS + W_ITEMS; i += stride) {
            if (i < X_ITEMS) {
                float4 v = x4[i];
                ushort4 o;
                o.x = f2bf(v.x); o.y = f2bf(v.y); o.z = f2bf(v.z); o.w = f2bf(v.w);
                xb4[i] = o;
            } else {
                int j = i - X_ITEMS;
                int c = j >> 7, k = j & 127;
                float v = (k < 64) ? W_rel[c * 64 + k] : W_root[c * 64 + (k - 64)];
                Wcat[j] = f2bf(v);
            }
        }
    }
}

// ---------------------------------------------------------------------------
// aggsort: LDS list -> counting sort -> WIDE-LOAD per-node gather.
// r20 insight: old gather used 2 B/lane loads (1 row / 128 B per instr);
// r18's unroll-16 null says outstanding-INSTRUCTION count is saturated, so
// widen each instruction instead: ushort4 = 8 B/lane, quarter q=lane>>4 owns
// row slot[j+q], f=lane&15 owns features 4f..4f+3 -> 4 rows / 512 B per
// instruction. Cross-quarter reduce via 2 shfl_xor rounds; 16-lane ushort4
// row write.
// ---------------------------------------------------------------------------
__global__ __launch_bounds__(1024) void aggsort_kernel(
    const unsigned short* __restrict__ x_bf,
    const int* __restrict__ counts,
    const unsigned* __restrict__ staging,
    unsigned short* __restrict__ agg_bf) {
    __shared__ unsigned list[TCAP];
    __shared__ unsigned slot[TCAP];
    __shared__ int segorig[BINB], segscan[BINB], segoff[BINB];
    __shared__ int cnt[NPP], nodeoff[NPP], curn[NPP];
    __shared__ int scan256[256];

    const int p = blockIdx.x;
    const int tid = threadIdx.x;

    // 1. per-segment counts + inclusive scan over 256
    if (tid < BINB) {
        int c = counts[tid * PARTS + p];
        segorig[tid] = c;
        segscan[tid] = c;
    }
    __syncthreads();
    for (int off = 1; off < BINB; off <<= 1) {
        int v = 0;
        if (tid < BINB && tid >= off) v = segscan[tid - off];
        __syncthreads();
        if (tid < BINB && tid >= off) segscan[tid] += v;
        __syncthreads();
    }
    if (tid < BINB) segoff[tid] = segscan[tid] - segorig[tid];  // exclusive
    __syncthreads();
    const int total = min(segscan[BINB - 1], TCAP);

    // copy segments into dense LDS list
    for (int k = tid; k < BINB * BCAP; k += 1024) {
        int seg = k / BCAP;
        int idx = k - seg * BCAP;
        if (idx < segorig[seg]) {
            int dp = segoff[seg] + idx;
            if (dp < TCAP)
                list[dp] = staging[((size_t)seg * PARTS + p) * BCAP + idx];
        }
    }
    // 2a. node histogram
    for (int i = tid; i < NPP; i += 1024) cnt[i] = 0;
    __syncthreads();
    for (int i = tid; i < total; i += 1024)
        atomicAdd(&cnt[list[i] >> 17], 1);
    __syncthreads();
    // 2b. inclusive scan over 196 (padded to 256)
    if (tid < 256) scan256[tid] = (tid < NPP) ? cnt[tid] : 0;
    __syncthreads();
    for (int off = 1; off < 256; off <<= 1) {
        int v = 0;
        if (tid < 256 && tid >= off) v = scan256[tid - off];
        __syncthreads();
        if (tid < 256 && tid >= off) scan256[tid] += v;
        __syncthreads();
    }
    if (tid < NPP) {
        int st = scan256[tid] - cnt[tid];   // exclusive
        nodeoff[tid] = st;
        curn[tid] = st;
    }
    __syncthreads();
    // 2c. scatter into sorted order (keep only src, 17 bits)
    for (int i = tid; i < total; i += 1024) {
        unsigned v = list[i];
        int r = (int)(v >> 17);
        int pos = atomicAdd(&curn[r], 1);
        slot[pos] = v & 0x1FFFFu;
    }
    __syncthreads();

    // 3. wide-load gather: quarter q owns row slot[j+q]; f owns 4 features.
    const int lane = tid & 63;
    const int w = tid >> 6;            // 0..15
    const int q = lane >> 4;           // 0..3 quarter
    const int f = lane & 15;           // feature-group (4f..4f+3)
    const ushort4* xb4v = (const ushort4*)x_bf;     // row = 16 ushort4
    for (int r = w; r < NPP; r += 16) {
        int node = p * NPP + r;
        if (node >= N_NODES) break;    // wave-uniform
        int beg = nodeoff[r];
        int end = beg + cnt[r];
        float a0 = 0.f, a1 = 0.f, a2 = 0.f, a3 = 0.f;
        int j = beg;
        for (; j + 8 <= end; j += 8) {    // 8 rows, 2 load instrs (2x512B)
            int sA = (int)slot[j + q];
            int sB = (int)slot[j + 4 + q];
            ushort4 uA = xb4v[(size_t)sA * 16 + f];
            ushort4 uB = xb4v[(size_t)sB * 16 + f];
            a0 += bf2f(uA.x); a1 += bf2f(uA.y); a2 += bf2f(uA.z); a3 += bf2f(uA.w);
            a0 += bf2f(uB.x); a1 += bf2f(uB.y); a2 += bf2f(uB.z); a3 += bf2f(uB.w);
        }
        for (; j + 4 <= end; j += 4) {    // 4 rows, 1 load instr
            int sA = (int)slot[j + q];
            ushort4 uA = xb4v[(size_t)sA * 16 + f];
            a0 += bf2f(uA.x); a1 += bf2f(uA.y); a2 += bf2f(uA.z); a3 += bf2f(uA.w);
        }
        if (j < end) {                     // tail 1..3 rows: masked quarter
            int t = end - j;
            int idx = (q < t) ? (int)slot[j + q] : (int)slot[beg];
            float m = (q < t) ? 1.f : 0.f;
            ushort4 u = xb4v[(size_t)idx * 16 + f];
            a0 += m * bf2f(u.x); a1 += m * bf2f(u.y);
            a2 += m * bf2f(u.z); a3 += m * bf2f(u.w);
        }
        // reduce across quarters (lanes f, f+16, f+32, f+48 share features)
        a0 += __shfl_xor(a0, 16); a0 += __shfl_xor(a0, 32);
        a1 += __shfl_xor(a1, 16); a1 += __shfl_xor(a1, 32);
        a2 += __shfl_xor(a2, 16); a2 += __shfl_xor(a2, 32);
        a3 += __shfl_xor(a3, 16); a3 += __shfl_xor(a3, 32);
        if (q == 0) {                      // 16 lanes write the 128B agg row
            ushort4 o;
            o.x = f2bf(a0); o.y = f2bf(a1); o.z = f2bf(a2); o.w = f2bf(a3);
            ((ushort4*)agg_bf)[(size_t)node * 16 + f] = o;
        }
    }
}

// ---------------------------------------------------------------------------
// MFMA transform (round-8 proven): out[n][c] = relu(agg.Wrel + x.Wroot + b)
// ---------------------------------------------------------------------------
__global__ __launch_bounds__(256, 2) void transform_mfma_kernel(
    const unsigned short* __restrict__ agg_bf,  // [N][64] bf16
    const unsigned short* __restrict__ x_bf,    // [N][64] bf16
    const unsigned short* __restrict__ Wcat,    // [64][128] bf16
    const float* __restrict__ b_rel,
    float* __restrict__ out) {
    const int lane = threadIdx.x & 63;
    const int lr = lane & 15;
    const int lh = lane >> 4;

    bf16x8 bfr[4][4];
    #pragma unroll
    for (int cg = 0; cg < 4; ++cg)
        #pragma unroll
        for (int kk = 0; kk < 4; ++kk)
            bfr[cg][kk] = *(const bf16x8*)(Wcat + (cg * 16 + lr) * 128 + kk * 32 + lh * 8);

    float bias[4];
    #pragma unroll
    for (int cg = 0; cg < 4; ++cg) bias[cg] = b_rel[cg * 16 + lr];

    int wid = (blockIdx.x * blockDim.x + threadIdx.x) >> 6;
    int nw  = (gridDim.x * blockDim.x) >> 6;

    for (int g = wid; g < NGROUPS; g += nw) {
        const unsigned short* Aa = agg_bf + (size_t)(g * 16 + lr) * 64;
        const unsigned short* Ax = x_bf   + (size_t)(g * 16 + lr) * 64;
        bf16x8 afr[4];
        #pragma unroll
        for (int kk = 0; kk < 2; ++kk) {
            afr[kk]     = *(const bf16x8*)(Aa + kk * 32 + lh * 8);
            afr[kk + 2] = *(const bf16x8*)(Ax + kk * 32 + lh * 8);
        }
        #pragma unroll
        for (int cg = 0; cg < 4; ++cg) {
            f32x4 acc = {0.f, 0.f, 0.f, 0.f};
            #pragma unroll
            for (int kk = 0; kk < 4; ++kk)
                acc = __builtin_amdgcn_mfma_f32_16x16x32_bf16(afr[kk], bfr[cg][kk], acc, 0, 0, 0);
            #pragma unroll
            for (int r = 0; r < 4; ++r)
                out[(size_t)(g * 16 + lh * 4 + r) * 64 + cg * 16 + lr] =
                    fmaxf(acc[r] + bias[cg], 0.f);
        }
    }
}

// ---------------------------------------------------------------------------
// Fallback path (needs no workspace): atomic scatter + fp32 transform
// ---------------------------------------------------------------------------
__global__ void zero_kernel(float4* __restrict__ p, int n4) {
    int i = blockIdx.x * blockDim.x + threadIdx.x;
    int stride = gridDim.x * blockDim.x;
    for (; i < n4; i += stride) p[i] = make_float4(0.f, 0.f, 0.f, 0.f);
}

__global__ void scatter_kernel(const float4* __restrict__ x4,
                               const int* __restrict__ src,
                               const int* __restrict__ dst,
                               float* __restrict__ agg) {
    int idx = blockIdx.x * blockDim.x + threadIdx.x;
    const int total = N_EDGES * 16;
    int stride = gridDim.x * blockDim.x;
    for (; idx < total; idx += stride) {
        int e = idx >> 4;
        int q = idx & 15;
        int s = src[e];
        int d = dst[e];
        float4 v = x4[s * 16 + q];
        float* base = agg + d * 64 + q * 4;
        unsafeAtomicAdd(base + 0, v.x);
        unsafeAtomicAdd(base + 1, v.y);
        unsafeAtomicAdd(base + 2, v.z);
        unsafeAtomicAdd(base + 3, v.w);
    }
}

__global__ __launch_bounds__(256, 1) void transform3_kernel(
    const float* __restrict__ x,
    const float* __restrict__ W_rel,
    const float* __restrict__ b_rel,
    const float* __restrict__ W_root,
    float* __restrict__ agg_out) {
    const int lane = threadIdx.x & 63;
    float4 wr[16], wo[16];
    const float4* Wr4 = (const float4*)W_rel;
    const float4* Wo4 = (const float4*)W_root;
    #pragma unroll
    for (int i = 0; i < 16; ++i) {
        float4 a = Wr4[lane * 16 + i];
        float4 b = Wo4[lane * 16 + i];
        asm volatile("" : "+v"(a.x), "+v"(a.y), "+v"(a.z), "+v"(a.w));
        asm volatile("" : "+v"(b.x), "+v"(b.y), "+v"(b.z), "+v"(b.w));
        wr[i] = a;
        wo[i] = b;
    }
    const float bias = b_rel[lane];
    int gwave = (blockIdx.x * blockDim.x + threadIdx.x) >> 6;
    int nwaves = (gridDim.x * blockDim.x) >> 6;
    for (int node = gwave; node < N_NODES; node += nwaves) {
        const float4* ar4 = (const float4*)(agg_out + (size_t)node * 64);
        const float4* xr4 = (const float4*)(x + (size_t)node * 64);
        float acc = bias;
        #pragma unroll
        for (int i = 0; i < 16; ++i) {
            float4 a = ar4[i];
            float4 v = xr4[i];
            acc += a.x * wr[i].x + a.y * wr[i].y + a.z * wr[i].z + a.w * wr[i].w;
            acc += v.x * wo[i].x + v.y * wo[i].y + v.z * wo[i].z + v.w * wo[i].w;
        }
        agg_out[(size_t)node * 64 + lane] = fmaxf(acc, 0.f);
    }
}

extern "C" void kernel_launch(void* const* d_in, const int* in_sizes, int n_in,
                              void* d_out, int out_size, void* d_ws, size_t ws_size,
                              hipStream_t stream) {
    const float* x      = (const float*)d_in[0];
    const int*   adj    = (const int*)d_in[1];   // delivered as int32 [2][N_EDGES]
    const float* W_rel  = (const float*)d_in[2];
    const float* b_rel  = (const float*)d_in[3];
    const float* W_root = (const float*)d_in[4];
    float*       out    = (float*)d_out;

    const int* src = adj;
    const int* dst = adj + N_EDGES;

    // ws: counts[BINB*PARTS] ints | x_bf | agg_bf | Wcat (bf16)
    // staging (256 blk x 511 parts x 48 x 4B = 25.1MB, BLOCK-major) lives in
    // d_out (25.6MB), fully consumed by aggsort BEFORE transform writes d_out.
    const size_t CNT_INTS = (size_t)BINB * PARTS;          // 130,816
    const size_t row_elems = (size_t)N_NODES * 64;
    const size_t bf_base = ((CNT_INTS * sizeof(int)) + 127) & ~(size_t)127;
    const size_t ws_needed = bf_base +
        (2 * row_elems + (size_t)NCLASS * 128) * sizeof(unsigned short);

    if (ws_size >= ws_needed) {
        int* counts = (int*)d_ws;
        unsigned short* x_bf   = (unsigned short*)((char*)d_ws + bf_base);
        unsigned short* agg_bf = x_bf + row_elems;
        unsigned short* Wcat   = agg_bf + row_elems;
        unsigned* staging = (unsigned*)d_out;

        prepbin_kernel<<<BINB + 2048, 256, 0, stream>>>(
            (const float4*)x, (ushort4*)x_bf, W_rel, W_root, Wcat,
            src, dst, counts, staging);
        aggsort_kernel<<<PARTS, 1024, 0, stream>>>(x_bf, counts, staging, agg_bf);
        transform_mfma_kernel<<<1024, 256, 0, stream>>>(agg_bf, x_bf, Wcat, b_rel, out);
    } else {
        zero_kernel<<<2048, 256, 0, stream>>>((float4*)out, (N_NODES * NFEAT) / 4);
        scatter_kernel<<<4096, 256, 0, stream>>>((const float4*)x, src, dst, out);
        transform3_kernel<<<1024, 256, 0, stream>>>(x, W_rel, b_rel, W_root, out);
    }
}